// Round 14
// baseline (482.365 us; speedup 1.0000x reference)
//
#include <hip/hip_runtime.h>

#define IN_F 4096
#define OUT_F 4096
#define NTOK 8192   // B*S = 4*2048
#define KDIM 4096

using i32x4 = __attribute__((ext_vector_type(4))) int;
using f32x4 = __attribute__((ext_vector_type(4))) float;

__device__ __forceinline__ void gload_lds16(const void* g, void* l) {
  __builtin_amdgcn_global_load_lds(
      (const __attribute__((address_space(1))) void*)g,
      (__attribute__((address_space(3))) void*)l, 16, 0, 0);
}

#define WAITV(n) asm volatile("s_waitcnt vmcnt(" #n ")" ::: "memory")
#define BAR() do { asm volatile("" ::: "memory"); __builtin_amdgcn_s_barrier(); \
                   asm volatile("" ::: "memory"); } while (0)

// -------- Pass 1 (fused): RMSNorm+quant  OR  W f32->i8 convert -------------
__global__ __launch_bounds__(256) void prep_kernel(
    const float* __restrict__ x, const float* __restrict__ rmsw,
    const float* __restrict__ W, signed char* __restrict__ q,
    signed char* __restrict__ Wq, float* __restrict__ dscale) {
  const int tid = threadIdx.x;
  if (blockIdx.x >= NTOK) {
    const int idx = (blockIdx.x - NTOK) * 256 + tid;  // float4 index
    f32x4 w = ((const f32x4*)W)[idx];
    uint p = ((uint)((int)w.x & 255)) | ((uint)((int)w.y & 255) << 8) |
             ((uint)((int)w.z & 255) << 16) | ((uint)((int)w.w & 255) << 24);
    ((uint*)Wq)[idx] = p;
    return;
  }
  const int tok = blockIdx.x;
  const f32x4* xr = (const f32x4*)(x + (size_t)tok * IN_F);
  const f32x4* wr = (const f32x4*)rmsw;

  f32x4 v[4];
  float ss = 0.f;
#pragma unroll
  for (int c = 0; c < 4; ++c) {
    v[c] = xr[c * 256 + tid];
    ss += v[c].x * v[c].x + v[c].y * v[c].y + v[c].z * v[c].z + v[c].w * v[c].w;
  }

  __shared__ float red[4];
#pragma unroll
  for (int off = 32; off > 0; off >>= 1) ss += __shfl_down(ss, off, 64);
  const int wid = tid >> 6;
  if ((tid & 63) == 0) red[wid] = ss;
  __syncthreads();
  const float tot = red[0] + red[1] + red[2] + red[3];
  const float rinv = rsqrtf(tot * (1.0f / IN_F) + 1e-6f);

  f32x4 h[4];
  float amax = 0.f;
#pragma unroll
  for (int c = 0; c < 4; ++c) {
    f32x4 w = wr[c * 256 + tid];
    h[c].x = v[c].x * rinv * w.x;
    h[c].y = v[c].y * rinv * w.y;
    h[c].z = v[c].z * rinv * w.z;
    h[c].w = v[c].w * rinv * w.w;
    amax = fmaxf(amax, fabsf(h[c].x));
    amax = fmaxf(amax, fabsf(h[c].y));
    amax = fmaxf(amax, fabsf(h[c].z));
    amax = fmaxf(amax, fabsf(h[c].w));
  }

  __syncthreads();
#pragma unroll
  for (int off = 32; off > 0; off >>= 1)
    amax = fmaxf(amax, __shfl_down(amax, off, 64));
  if ((tid & 63) == 0) red[wid] = amax;
  __syncthreads();
  amax = fmaxf(fmaxf(red[0], red[1]), fmaxf(red[2], red[3]));
  amax = fmaxf(amax, 1e-5f);
  const float qs = 127.0f / amax;
  if (tid == 0) dscale[tok] = amax * (1.0f / 127.0f);

  uint* qo = (uint*)(q + (size_t)tok * IN_F);
#pragma unroll
  for (int c = 0; c < 4; ++c) {
    float r0 = fminf(fmaxf(rintf(h[c].x * qs), -128.f), 127.f);
    float r1 = fminf(fmaxf(rintf(h[c].y * qs), -128.f), 127.f);
    float r2 = fminf(fmaxf(rintf(h[c].z * qs), -128.f), 127.f);
    float r3 = fminf(fmaxf(rintf(h[c].w * qs), -128.f), 127.f);
    uint p = ((uint)((int)r0 & 255)) | ((uint)((int)r1 & 255) << 8) |
             ((uint)((int)r2 & 255) << 16) | ((uint)((int)r3 & 255) << 24);
    qo[c * 256 + tid] = p;
  }
}

// ---------------- Pass 2: int8 GEMM, 3 blocks/CU, XCD-pair mapping ---------
// 128x256 tile, BK=64, 4 waves. NBUF=2 (48 KB LDS -> 3 blocks/CU = 12
// waves/CU): when one block sits at its barrier, waves of the other two fill
// the MFMA pipe (m114 implicit overlap). Depth-1 prefetch (STAGE(t+1)
// mid-tile), WAITV(0) at tile top (free: issue->need gap ~2700cy >> 900cy
// HBM). One BAR/tile; safety: wave Y reaches BAR(t) only after its t-1
// MFMAs (reads lgkm-complete), so post-BAR STAGE(t+1) never overwrites
// live reads. XCD-pair map (FETCH 124 MB, verified R13) unchanged.
#define BM 128
#define BN 256
#define BK 64
#define NT (KDIM / BK)       // 64 K-tiles
#define ATILEB (BM * BK)     // 8192
#define BTILEB (BN * BK)     // 16384
#define BUFB (ATILEB + BTILEB)  // 24576
#define NBUF 2

__global__ __launch_bounds__(256, 3) void gemm_kernel(
    const signed char* __restrict__ A, const signed char* __restrict__ Bw,
    const float* __restrict__ dscale, const float* __restrict__ bias,
    const float* __restrict__ wscale_p, float* __restrict__ out) {
  __shared__ __align__(16) signed char lds[NBUF * BUFB];  // 48 KB

  const int tid = threadIdx.x;
  const int lane = tid & 63;
  const int wc = tid >> 6;   // 0..3 : 64 output cols each

  // XCD-pair mapping (1024 blocks; bid&7 = XCD by hw round-robin):
  // pair = x>>1 owns n-blocks [4*pair, 4*pair+4); member x&1 owns m-half.
  const int bid = blockIdx.x;
  const int x = bid & 7;
  const int j = bid >> 3;                        // 0..127
  const int m0 = ((x & 1) * 32 + (j >> 2)) * BM; // 64 m-blocks
  const int n0 = ((x >> 1) * 4 + (j & 3)) * BN;  // 16 n-blocks

  // staging: unit u -> row r=u>>2, phys slot p=u&3 holds logical slot
  // s = p ^ ((r>>1)&3)  (pre-swizzled global source, linear LDS dest)
  const int cA0 = tid, cA1 = tid + 256;          // A: 512 units
  const int rA0 = cA0 >> 2, rA1 = cA1 >> 2;
  const int sA0 = (cA0 & 3) ^ ((rA0 >> 1) & 3);
  const int sA1 = (cA1 & 3) ^ ((rA1 >> 1) & 3);
  const signed char* agp0 = A + (size_t)(m0 + rA0) * KDIM + sA0 * 16;
  const signed char* agp1 = A + (size_t)(m0 + rA1) * KDIM + sA1 * 16;
  // B: 1024 units, rows 0..255
  const signed char* bgp[4];
#pragma unroll
  for (int jj = 0; jj < 4; ++jj) {
    const int rBj = (tid >> 2) + jj * 64;
    const int sBj = (tid & 3) ^ ((rBj >> 1) & 3);
    bgp[jj] = Bw + (size_t)(n0 + rBj) * KDIM + sBj * 16;
  }

#define STAGE(kt, boff)                                                    \
  do {                                                                     \
    const int k0_ = (kt) * BK;                                             \
    signed char* lb_ = &lds[(boff)];                                       \
    gload_lds16(agp0 + k0_, lb_ + cA0 * 16);                               \
    gload_lds16(agp1 + k0_, lb_ + cA1 * 16);                               \
    gload_lds16(bgp[0] + k0_, lb_ + ATILEB + (tid + 0 * 256) * 16);        \
    gload_lds16(bgp[1] + k0_, lb_ + ATILEB + (tid + 1 * 256) * 16);        \
    gload_lds16(bgp[2] + k0_, lb_ + ATILEB + (tid + 2 * 256) * 16);        \
    gload_lds16(bgp[3] + k0_, lb_ + ATILEB + (tid + 3 * 256) * 16);        \
  } while (0)

  // fragment read offsets (R6 swizzle, measured conflict-free)
  const int fr = lane & 15;
  const int ks = lane >> 4;
  int offA[8], offB[4];
#pragma unroll
  for (int mi = 0; mi < 8; ++mi) {
    const int row = mi * 16 + fr;
    offA[mi] = (row * 4 + (ks ^ ((row >> 1) & 3))) * 16;
  }
#pragma unroll
  for (int ni = 0; ni < 4; ++ni) {
    const int row = wc * 64 + ni * 16 + fr;
    offB[ni] = ATILEB + (row * 4 + (ks ^ ((row >> 1) & 3))) * 16;
  }

  i32x4 acc[8][4];
#pragma unroll
  for (int i = 0; i < 8; ++i)
#pragma unroll
    for (int jj = 0; jj < 4; ++jj) acc[i][jj] = (i32x4){0, 0, 0, 0};

  // prologue: stage tile 0 only (depth-1)
  STAGE(0, 0);

  int br = 0;             // buffer holding tile t
  int bs = BUFB;          // buffer to stage tile t+1 into
  for (int t = 0; t < NT; ++t) {
    WAITV(0);             // own tile-t loads landed (free in steady state)
    BAR();                // everyone's landed; everyone done with buf[t+1%2]

    const signed char* bp = &lds[br];
    i32x4 af[8], bf[4];
#pragma unroll
    for (int mi = 0; mi < 8; ++mi) af[mi] = *(const i32x4*)(bp + offA[mi]);
#pragma unroll
    for (int ni = 0; ni < 4; ++ni) bf[ni] = *(const i32x4*)(bp + offB[ni]);

    if (t + 1 < NT) STAGE(t + 1, bs);

    __builtin_amdgcn_s_setprio(1);
#pragma unroll
    for (int mi = 0; mi < 8; ++mi)
#pragma unroll
      for (int ni = 0; ni < 4; ++ni)
        acc[mi][ni] = __builtin_amdgcn_mfma_i32_16x16x64_i8(af[mi], bf[ni],
                                                            acc[mi][ni], 0, 0, 0);
    __builtin_amdgcn_s_setprio(0);

    br ^= BUFB;
    bs ^= BUFB;
  }

  // epilogue: dequant + bias + weight_scale
  const float wsc = wscale_p[0];
  const int rbase = (lane >> 4) * 4;
  float bv[4];
#pragma unroll
  for (int ni = 0; ni < 4; ++ni) bv[ni] = bias[n0 + wc * 64 + ni * 16 + fr];
#pragma unroll
  for (int mi = 0; mi < 8; ++mi) {
#pragma unroll
    for (int r = 0; r < 4; ++r) {
      const int m = m0 + mi * 16 + rbase + r;
      const float ds = dscale[m];
      float* orow = out + (size_t)m * OUT_F + n0 + wc * 64;
#pragma unroll
      for (int ni = 0; ni < 4; ++ni) {
        orow[ni * 16 + fr] = ((float)acc[mi][ni][r] * ds + bv[ni]) * wsc;
      }
    }
  }
#undef STAGE
}

extern "C" void kernel_launch(void* const* d_in, const int* in_sizes, int n_in,
                              void* d_out, int out_size, void* d_ws, size_t ws_size,
                              hipStream_t stream) {
  const float* x = (const float*)d_in[0];
  const float* W = (const float*)d_in[1];
  const float* rmsw = (const float*)d_in[2];
  const float* bias = (const float*)d_in[3];
  const float* wscale = (const float*)d_in[4];
  float* out = (float*)d_out;

  signed char* q = (signed char*)d_ws;                     // 32 MB
  signed char* Wq = q + (size_t)NTOK * IN_F;               // 16 MB
  float* dscale = (float*)(Wq + (size_t)OUT_F * IN_F);     // 32 KB

  prep_kernel<<<NTOK + (OUT_F * IN_F / 4) / 256, 256, 0, stream>>>(
      x, rmsw, W, q, Wq, dscale);
  gemm_kernel<<<(NTOK / BM) * (OUT_F / BN), 256, 0, stream>>>(q, Wq, dscale,
                                                              bias, wscale, out);
}

// Round 15
// 179.069 us; speedup vs baseline: 2.6937x; 2.6937x over previous
//
#include <hip/hip_runtime.h>

#define IN_F 4096
#define OUT_F 4096
#define NTOK 8192   // B*S = 4*2048
#define KDIM 4096

using i32x4 = __attribute__((ext_vector_type(4))) int;
using f32x4 = __attribute__((ext_vector_type(4))) float;

__device__ __forceinline__ void gload_lds16(const void* g, void* l) {
  __builtin_amdgcn_global_load_lds(
      (const __attribute__((address_space(1))) void*)g,
      (__attribute__((address_space(3))) void*)l, 16, 0, 0);
}

#define WAITV(n) asm volatile("s_waitcnt vmcnt(" #n ")" ::: "memory")
#define BAR() do { asm volatile("" ::: "memory"); __builtin_amdgcn_s_barrier(); \
                   asm volatile("" ::: "memory"); } while (0)

// -------- Pass 1 (fused): RMSNorm+quant  OR  W f32->i8 convert -------------
__global__ __launch_bounds__(256) void prep_kernel(
    const float* __restrict__ x, const float* __restrict__ rmsw,
    const float* __restrict__ W, signed char* __restrict__ q,
    signed char* __restrict__ Wq, float* __restrict__ dscale) {
  const int tid = threadIdx.x;
  if (blockIdx.x >= NTOK) {
    const int idx = (blockIdx.x - NTOK) * 256 + tid;  // float4 index
    f32x4 w = ((const f32x4*)W)[idx];
    uint p = ((uint)((int)w.x & 255)) | ((uint)((int)w.y & 255) << 8) |
             ((uint)((int)w.z & 255) << 16) | ((uint)((int)w.w & 255) << 24);
    ((uint*)Wq)[idx] = p;
    return;
  }
  const int tok = blockIdx.x;
  const f32x4* xr = (const f32x4*)(x + (size_t)tok * IN_F);
  const f32x4* wr = (const f32x4*)rmsw;

  f32x4 v[4];
  float ss = 0.f;
#pragma unroll
  for (int c = 0; c < 4; ++c) {
    v[c] = xr[c * 256 + tid];
    ss += v[c].x * v[c].x + v[c].y * v[c].y + v[c].z * v[c].z + v[c].w * v[c].w;
  }

  __shared__ float red[4];
#pragma unroll
  for (int off = 32; off > 0; off >>= 1) ss += __shfl_down(ss, off, 64);
  const int wid = tid >> 6;
  if ((tid & 63) == 0) red[wid] = ss;
  __syncthreads();
  const float tot = red[0] + red[1] + red[2] + red[3];
  const float rinv = rsqrtf(tot * (1.0f / IN_F) + 1e-6f);

  f32x4 h[4];
  float amax = 0.f;
#pragma unroll
  for (int c = 0; c < 4; ++c) {
    f32x4 w = wr[c * 256 + tid];
    h[c].x = v[c].x * rinv * w.x;
    h[c].y = v[c].y * rinv * w.y;
    h[c].z = v[c].z * rinv * w.z;
    h[c].w = v[c].w * rinv * w.w;
    amax = fmaxf(amax, fabsf(h[c].x));
    amax = fmaxf(amax, fabsf(h[c].y));
    amax = fmaxf(amax, fabsf(h[c].z));
    amax = fmaxf(amax, fabsf(h[c].w));
  }

  __syncthreads();
#pragma unroll
  for (int off = 32; off > 0; off >>= 1)
    amax = fmaxf(amax, __shfl_down(amax, off, 64));
  if ((tid & 63) == 0) red[wid] = amax;
  __syncthreads();
  amax = fmaxf(fmaxf(red[0], red[1]), fmaxf(red[2], red[3]));
  amax = fmaxf(amax, 1e-5f);
  const float qs = 127.0f / amax;
  if (tid == 0) dscale[tok] = amax * (1.0f / 127.0f);

  uint* qo = (uint*)(q + (size_t)tok * IN_F);
#pragma unroll
  for (int c = 0; c < 4; ++c) {
    float r0 = fminf(fmaxf(rintf(h[c].x * qs), -128.f), 127.f);
    float r1 = fminf(fmaxf(rintf(h[c].y * qs), -128.f), 127.f);
    float r2 = fminf(fmaxf(rintf(h[c].z * qs), -128.f), 127.f);
    float r3 = fminf(fmaxf(rintf(h[c].w * qs), -128.f), 127.f);
    uint p = ((uint)((int)r0 & 255)) | ((uint)((int)r1 & 255) << 8) |
             ((uint)((int)r2 & 255) << 16) | ((uint)((int)r3 & 255) << 24);
    qo[c * 256 + tid] = p;
  }
}

// ---------------- Pass 2: int8 GEMM, 3 blocks/CU, XCD-pair mapping ---------
// 128x256 tile, BK=64, 4 waves. NBUF=2 (48 KB LDS -> 3 blocks/CU = 12
// waves/CU, LDS-limited). launch_bounds(256,2): allocator cap 256 VGPR —
// R14's (256,3) capped at ~170 and SPILLED acc to scratch (WRITE_SIZE 1 GB,
// 586 µs). Depth-1 prefetch (STAGE(t+1) mid-tile), WAITV(0) at tile top
// (issue->need gap ~2700cy >> 900cy HBM; 3-block TLP covers the rest).
// One BAR/tile. XCD-pair map (FETCH 124 MB, verified R13) unchanged.
#define BM 128
#define BN 256
#define BK 64
#define NT (KDIM / BK)       // 64 K-tiles
#define ATILEB (BM * BK)     // 8192
#define BTILEB (BN * BK)     // 16384
#define BUFB (ATILEB + BTILEB)  // 24576
#define NBUF 2

__global__ __launch_bounds__(256, 2) void gemm_kernel(
    const signed char* __restrict__ A, const signed char* __restrict__ Bw,
    const float* __restrict__ dscale, const float* __restrict__ bias,
    const float* __restrict__ wscale_p, float* __restrict__ out) {
  __shared__ __align__(16) signed char lds[NBUF * BUFB];  // 48 KB

  const int tid = threadIdx.x;
  const int lane = tid & 63;
  const int wc = tid >> 6;   // 0..3 : 64 output cols each

  // XCD-pair mapping (1024 blocks; bid&7 = XCD by hw round-robin):
  // pair = x>>1 owns n-blocks [4*pair, 4*pair+4); member x&1 owns m-half.
  const int bid = blockIdx.x;
  const int x = bid & 7;
  const int j = bid >> 3;                        // 0..127
  const int m0 = ((x & 1) * 32 + (j >> 2)) * BM; // 64 m-blocks
  const int n0 = ((x >> 1) * 4 + (j & 3)) * BN;  // 16 n-blocks

  // staging: unit u -> row r=u>>2, phys slot p=u&3 holds logical slot
  // s = p ^ ((r>>1)&3)  (pre-swizzled global source, linear LDS dest)
  const int cA0 = tid, cA1 = tid + 256;          // A: 512 units
  const int rA0 = cA0 >> 2, rA1 = cA1 >> 2;
  const int sA0 = (cA0 & 3) ^ ((rA0 >> 1) & 3);
  const int sA1 = (cA1 & 3) ^ ((rA1 >> 1) & 3);
  const signed char* agp0 = A + (size_t)(m0 + rA0) * KDIM + sA0 * 16;
  const signed char* agp1 = A + (size_t)(m0 + rA1) * KDIM + sA1 * 16;
  // B: 1024 units, rows 0..255
  const signed char* bgp[4];
#pragma unroll
  for (int jj = 0; jj < 4; ++jj) {
    const int rBj = (tid >> 2) + jj * 64;
    const int sBj = (tid & 3) ^ ((rBj >> 1) & 3);
    bgp[jj] = Bw + (size_t)(n0 + rBj) * KDIM + sBj * 16;
  }

#define STAGE(kt, boff)                                                    \
  do {                                                                     \
    const int k0_ = (kt) * BK;                                             \
    signed char* lb_ = &lds[(boff)];                                       \
    gload_lds16(agp0 + k0_, lb_ + cA0 * 16);                               \
    gload_lds16(agp1 + k0_, lb_ + cA1 * 16);                               \
    gload_lds16(bgp[0] + k0_, lb_ + ATILEB + (tid + 0 * 256) * 16);        \
    gload_lds16(bgp[1] + k0_, lb_ + ATILEB + (tid + 1 * 256) * 16);        \
    gload_lds16(bgp[2] + k0_, lb_ + ATILEB + (tid + 2 * 256) * 16);        \
    gload_lds16(bgp[3] + k0_, lb_ + ATILEB + (tid + 3 * 256) * 16);        \
  } while (0)

  // fragment read offsets (R6 swizzle, measured conflict-free)
  const int fr = lane & 15;
  const int ks = lane >> 4;
  int offA[8], offB[4];
#pragma unroll
  for (int mi = 0; mi < 8; ++mi) {
    const int row = mi * 16 + fr;
    offA[mi] = (row * 4 + (ks ^ ((row >> 1) & 3))) * 16;
  }
#pragma unroll
  for (int ni = 0; ni < 4; ++ni) {
    const int row = wc * 64 + ni * 16 + fr;
    offB[ni] = ATILEB + (row * 4 + (ks ^ ((row >> 1) & 3))) * 16;
  }

  i32x4 acc[8][4];
#pragma unroll
  for (int i = 0; i < 8; ++i)
#pragma unroll
    for (int jj = 0; jj < 4; ++jj) acc[i][jj] = (i32x4){0, 0, 0, 0};

  // prologue: stage tile 0 only (depth-1)
  STAGE(0, 0);

  int br = 0;             // buffer holding tile t
  int bs = BUFB;          // buffer to stage tile t+1 into
  for (int t = 0; t < NT; ++t) {
    WAITV(0);             // own tile-t loads landed
    BAR();                // everyone's landed; everyone done with stage target

    const signed char* bp = &lds[br];
    i32x4 af[8], bf[4];
#pragma unroll
    for (int mi = 0; mi < 8; ++mi) af[mi] = *(const i32x4*)(bp + offA[mi]);
#pragma unroll
    for (int ni = 0; ni < 4; ++ni) bf[ni] = *(const i32x4*)(bp + offB[ni]);

    if (t + 1 < NT) STAGE(t + 1, bs);

    __builtin_amdgcn_s_setprio(1);
#pragma unroll
    for (int mi = 0; mi < 8; ++mi)
#pragma unroll
      for (int ni = 0; ni < 4; ++ni)
        acc[mi][ni] = __builtin_amdgcn_mfma_i32_16x16x64_i8(af[mi], bf[ni],
                                                            acc[mi][ni], 0, 0, 0);
    __builtin_amdgcn_s_setprio(0);

    br ^= BUFB;
    bs ^= BUFB;
  }

  // epilogue: dequant + bias + weight_scale
  const float wsc = wscale_p[0];
  const int rbase = (lane >> 4) * 4;
  float bv[4];
#pragma unroll
  for (int ni = 0; ni < 4; ++ni) bv[ni] = bias[n0 + wc * 64 + ni * 16 + fr];
#pragma unroll
  for (int mi = 0; mi < 8; ++mi) {
#pragma unroll
    for (int r = 0; r < 4; ++r) {
      const int m = m0 + mi * 16 + rbase + r;
      const float ds = dscale[m];
      float* orow = out + (size_t)m * OUT_F + n0 + wc * 64;
#pragma unroll
      for (int ni = 0; ni < 4; ++ni) {
        orow[ni * 16 + fr] = ((float)acc[mi][ni][r] * ds + bv[ni]) * wsc;
      }
    }
  }
#undef STAGE
}

extern "C" void kernel_launch(void* const* d_in, const int* in_sizes, int n_in,
                              void* d_out, int out_size, void* d_ws, size_t ws_size,
                              hipStream_t stream) {
  const float* x = (const float*)d_in[0];
  const float* W = (const float*)d_in[1];
  const float* rmsw = (const float*)d_in[2];
  const float* bias = (const float*)d_in[3];
  const float* wscale = (const float*)d_in[4];
  float* out = (float*)d_out;

  signed char* q = (signed char*)d_ws;                     // 32 MB
  signed char* Wq = q + (size_t)NTOK * IN_F;               // 16 MB
  float* dscale = (float*)(Wq + (size_t)OUT_F * IN_F);     // 32 KB

  prep_kernel<<<NTOK + (OUT_F * IN_F / 4) / 256, 256, 0, stream>>>(
      x, rmsw, W, q, Wq, dscale);
  gemm_kernel<<<(NTOK / BM) * (OUT_F / BN), 256, 0, stream>>>(q, Wq, dscale,
                                                              bias, wscale, out);
}

// Round 16
// 178.545 us; speedup vs baseline: 2.7016x; 1.0029x over previous
//
#include <hip/hip_runtime.h>

#define IN_F 4096
#define OUT_F 4096
#define NTOK 8192   // B*S = 4*2048
#define KDIM 4096

using i32x4 = __attribute__((ext_vector_type(4))) int;
using f32x4 = __attribute__((ext_vector_type(4))) float;

__device__ __forceinline__ void gload_lds16(const void* g, void* l) {
  __builtin_amdgcn_global_load_lds(
      (const __attribute__((address_space(1))) void*)g,
      (__attribute__((address_space(3))) void*)l, 16, 0, 0);
}

#define WAITV(n) asm volatile("s_waitcnt vmcnt(" #n ")" ::: "memory")
#define BAR() do { asm volatile("" ::: "memory"); __builtin_amdgcn_s_barrier(); \
                   asm volatile("" ::: "memory"); } while (0)

// -------- Pass 1 (fused): RMSNorm+quant  OR  W f32->i8 convert -------------
// HBM-roofline bound (~246 MB): x 134 R + q 32 W + W 64 R + Wq 16 W.
__global__ __launch_bounds__(256) void prep_kernel(
    const float* __restrict__ x, const float* __restrict__ rmsw,
    const float* __restrict__ W, signed char* __restrict__ q,
    signed char* __restrict__ Wq, float* __restrict__ dscale) {
  const int tid = threadIdx.x;
  if (blockIdx.x >= NTOK) {
    const int idx = (blockIdx.x - NTOK) * 256 + tid;  // float4 index
    f32x4 w = ((const f32x4*)W)[idx];
    uint p = ((uint)((int)w.x & 255)) | ((uint)((int)w.y & 255) << 8) |
             ((uint)((int)w.z & 255) << 16) | ((uint)((int)w.w & 255) << 24);
    ((uint*)Wq)[idx] = p;
    return;
  }
  const int tok = blockIdx.x;
  const f32x4* xr = (const f32x4*)(x + (size_t)tok * IN_F);
  const f32x4* wr = (const f32x4*)rmsw;

  f32x4 v[4];
  float ss = 0.f;
#pragma unroll
  for (int c = 0; c < 4; ++c) {
    v[c] = xr[c * 256 + tid];
    ss += v[c].x * v[c].x + v[c].y * v[c].y + v[c].z * v[c].z + v[c].w * v[c].w;
  }

  __shared__ float red[4];
#pragma unroll
  for (int off = 32; off > 0; off >>= 1) ss += __shfl_down(ss, off, 64);
  const int wid = tid >> 6;
  if ((tid & 63) == 0) red[wid] = ss;
  __syncthreads();
  const float tot = red[0] + red[1] + red[2] + red[3];
  const float rinv = rsqrtf(tot * (1.0f / IN_F) + 1e-6f);

  f32x4 h[4];
  float amax = 0.f;
#pragma unroll
  for (int c = 0; c < 4; ++c) {
    f32x4 w = wr[c * 256 + tid];
    h[c].x = v[c].x * rinv * w.x;
    h[c].y = v[c].y * rinv * w.y;
    h[c].z = v[c].z * rinv * w.z;
    h[c].w = v[c].w * rinv * w.w;
    amax = fmaxf(amax, fabsf(h[c].x));
    amax = fmaxf(amax, fabsf(h[c].y));
    amax = fmaxf(amax, fabsf(h[c].z));
    amax = fmaxf(amax, fabsf(h[c].w));
  }

  __syncthreads();
#pragma unroll
  for (int off = 32; off > 0; off >>= 1)
    amax = fmaxf(amax, __shfl_down(amax, off, 64));
  if ((tid & 63) == 0) red[wid] = amax;
  __syncthreads();
  amax = fmaxf(fmaxf(red[0], red[1]), fmaxf(red[2], red[3]));
  amax = fmaxf(amax, 1e-5f);
  const float qs = 127.0f / amax;
  if (tid == 0) dscale[tok] = amax * (1.0f / 127.0f);

  uint* qo = (uint*)(q + (size_t)tok * IN_F);
#pragma unroll
  for (int c = 0; c < 4; ++c) {
    float r0 = fminf(fmaxf(rintf(h[c].x * qs), -128.f), 127.f);
    float r1 = fminf(fmaxf(rintf(h[c].y * qs), -128.f), 127.f);
    float r2 = fminf(fmaxf(rintf(h[c].z * qs), -128.f), 127.f);
    float r3 = fminf(fmaxf(rintf(h[c].w * qs), -128.f), 127.f);
    uint p = ((uint)((int)r0 & 255)) | ((uint)((int)r1 & 255) << 8) |
             ((uint)((int)r2 & 255) << 16) | ((uint)((int)r3 & 255) << 24);
    qo[c * 256 + tid] = p;
  }
}

// ---------------- Pass 2: int8 GEMM (best measured config, R13) ------------
// 128x256 tile, BK=64, 4 waves, NBUF=3 (72 KB), depth-2 prefetch, WAITV(6),
// one barrier/tile, XCD-pair mapping (FETCH 98-124 MB verified).
// Occupancy is UNIFIED-REGISTER capped at 2 blocks/CU (228 regs/wave:
// 100 VGPR + 128 AGPR acc; 2048-pool / 228 = 8.9 waves) — R15 proved LDS
// headroom doesn't add blocks. Change vs R13: STAGE(t+2) issued BEFORE the
// fragment ds_reads (loads start ~150cy earlier; WAITV(6) accounting
// unchanged: S(t) still followed by exactly S(t+1)'s 6 loads).
#define BM 128
#define BN 256
#define BK 64
#define NT (KDIM / BK)       // 64 K-tiles
#define ATILEB (BM * BK)     // 8192
#define BTILEB (BN * BK)     // 16384
#define BUFB (ATILEB + BTILEB)  // 24576
#define NBUF 3

__global__ __launch_bounds__(256, 2) void gemm_kernel(
    const signed char* __restrict__ A, const signed char* __restrict__ Bw,
    const float* __restrict__ dscale, const float* __restrict__ bias,
    const float* __restrict__ wscale_p, float* __restrict__ out) {
  __shared__ __align__(16) signed char lds[NBUF * BUFB];  // 72 KB

  const int tid = threadIdx.x;
  const int lane = tid & 63;
  const int wc = tid >> 6;   // 0..3 : 64 output cols each

  // XCD-pair mapping (1024 blocks; bid&7 = XCD by hw round-robin):
  // pair = x>>1 owns n-blocks [4*pair, 4*pair+4); member x&1 owns m-half.
  const int bid = blockIdx.x;
  const int x = bid & 7;
  const int j = bid >> 3;                        // 0..127
  const int m0 = ((x & 1) * 32 + (j >> 2)) * BM; // 64 m-blocks
  const int n0 = ((x >> 1) * 4 + (j & 3)) * BN;  // 16 n-blocks

  // staging: unit u -> row r=u>>2, phys slot p=u&3 holds logical slot
  // s = p ^ ((r>>1)&3)  (pre-swizzled global source, linear LDS dest)
  const int cA0 = tid, cA1 = tid + 256;          // A: 512 units
  const int rA0 = cA0 >> 2, rA1 = cA1 >> 2;
  const int sA0 = (cA0 & 3) ^ ((rA0 >> 1) & 3);
  const int sA1 = (cA1 & 3) ^ ((rA1 >> 1) & 3);
  const signed char* agp0 = A + (size_t)(m0 + rA0) * KDIM + sA0 * 16;
  const signed char* agp1 = A + (size_t)(m0 + rA1) * KDIM + sA1 * 16;
  // B: 1024 units, rows 0..255
  const signed char* bgp[4];
#pragma unroll
  for (int jj = 0; jj < 4; ++jj) {
    const int rBj = (tid >> 2) + jj * 64;
    const int sBj = (tid & 3) ^ ((rBj >> 1) & 3);
    bgp[jj] = Bw + (size_t)(n0 + rBj) * KDIM + sBj * 16;
  }

#define STAGE(kt, boff)                                                    \
  do {                                                                     \
    const int k0_ = (kt) * BK;                                             \
    signed char* lb_ = &lds[(boff)];                                       \
    gload_lds16(agp0 + k0_, lb_ + cA0 * 16);                               \
    gload_lds16(agp1 + k0_, lb_ + cA1 * 16);                               \
    gload_lds16(bgp[0] + k0_, lb_ + ATILEB + (tid + 0 * 256) * 16);        \
    gload_lds16(bgp[1] + k0_, lb_ + ATILEB + (tid + 1 * 256) * 16);        \
    gload_lds16(bgp[2] + k0_, lb_ + ATILEB + (tid + 2 * 256) * 16);        \
    gload_lds16(bgp[3] + k0_, lb_ + ATILEB + (tid + 3 * 256) * 16);        \
  } while (0)

  // fragment read offsets (R6 swizzle, measured conflict-free)
  const int fr = lane & 15;
  const int ks = lane >> 4;
  int offA[8], offB[4];
#pragma unroll
  for (int mi = 0; mi < 8; ++mi) {
    const int row = mi * 16 + fr;
    offA[mi] = (row * 4 + (ks ^ ((row >> 1) & 3))) * 16;
  }
#pragma unroll
  for (int ni = 0; ni < 4; ++ni) {
    const int row = wc * 64 + ni * 16 + fr;
    offB[ni] = ATILEB + (row * 4 + (ks ^ ((row >> 1) & 3))) * 16;
  }

  i32x4 acc[8][4];
#pragma unroll
  for (int i = 0; i < 8; ++i)
#pragma unroll
    for (int jj = 0; jj < 4; ++jj) acc[i][jj] = (i32x4){0, 0, 0, 0};

  // prologue: depth-2 fill (tile-0 guard is the loop's WAITV(6))
  STAGE(0, 0);
  STAGE(1, BUFB);

  int br = 0;             // buffer holding tile t
  int bs = 2 * BUFB;      // buffer to stage tile t+2 into
  for (int t = 0; t < NT; ++t) {
    if (t < NT - 1) WAITV(6); else WAITV(0);
    BAR();  // everyone's tile-t chunks visible; everyone done reading
            // buf[(t-1)%3] == stage target below

    // issue next-next tile's loads FIRST (overlap with ds_reads + MFMA)
    if (t + 2 < NT) STAGE(t + 2, bs);

    const signed char* bp = &lds[br];
    i32x4 af[8], bf[4];
#pragma unroll
    for (int mi = 0; mi < 8; ++mi) af[mi] = *(const i32x4*)(bp + offA[mi]);
#pragma unroll
    for (int ni = 0; ni < 4; ++ni) bf[ni] = *(const i32x4*)(bp + offB[ni]);

    __builtin_amdgcn_s_setprio(1);
#pragma unroll
    for (int mi = 0; mi < 8; ++mi)
#pragma unroll
      for (int ni = 0; ni < 4; ++ni)
        acc[mi][ni] = __builtin_amdgcn_mfma_i32_16x16x64_i8(af[mi], bf[ni],
                                                            acc[mi][ni], 0, 0, 0);
    __builtin_amdgcn_s_setprio(0);

    br += BUFB; if (br == NBUF * BUFB) br = 0;
    bs += BUFB; if (bs == NBUF * BUFB) bs = 0;
  }

  // epilogue: dequant + bias + weight_scale
  const float wsc = wscale_p[0];
  const int rbase = (lane >> 4) * 4;
  float bv[4];
#pragma unroll
  for (int ni = 0; ni < 4; ++ni) bv[ni] = bias[n0 + wc * 64 + ni * 16 + fr];
#pragma unroll
  for (int mi = 0; mi < 8; ++mi) {
#pragma unroll
    for (int r = 0; r < 4; ++r) {
      const int m = m0 + mi * 16 + rbase + r;
      const float ds = dscale[m];
      float* orow = out + (size_t)m * OUT_F + n0 + wc * 64;
#pragma unroll
      for (int ni = 0; ni < 4; ++ni) {
        orow[ni * 16 + fr] = ((float)acc[mi][ni][r] * ds + bv[ni]) * wsc;
      }
    }
  }
#undef STAGE
}

extern "C" void kernel_launch(void* const* d_in, const int* in_sizes, int n_in,
                              void* d_out, int out_size, void* d_ws, size_t ws_size,
                              hipStream_t stream) {
  const float* x = (const float*)d_in[0];
  const float* W = (const float*)d_in[1];
  const float* rmsw = (const float*)d_in[2];
  const float* bias = (const float*)d_in[3];
  const float* wscale = (const float*)d_in[4];
  float* out = (float*)d_out;

  signed char* q = (signed char*)d_ws;                     // 32 MB
  signed char* Wq = q + (size_t)NTOK * IN_F;               // 16 MB
  float* dscale = (float*)(Wq + (size_t)OUT_F * IN_F);     // 32 KB

  prep_kernel<<<NTOK + (OUT_F * IN_F / 4) / 256, 256, 0, stream>>>(
      x, rmsw, W, q, Wq, dscale);
  gemm_kernel<<<(NTOK / BM) * (OUT_F / BN), 256, 0, stream>>>(q, Wq, dscale,
                                                              bias, wscale, out);
}